// Round 14
// baseline (148.525 us; speedup 1.0000x reference)
//
#include <hip/hip_runtime.h>
#include <hip/hip_bf16.h>

// PointConv: N=32768 points, E=786432 edges (sorted by out_index), K<=64
// product[n][c][m] = inv_n * sum_edges x_in[src][c] * celu(celu(pos_local@W1)@W2)[m]
// out[n][k] = product[n].flat(1024) @ W3[1024][64] + b3[k]
//
// R24: 16 waves x 1024 threads x 64 points/block (512 blocks).
// - Epilogue W3frag L2 traffic halves again (64MB total); 16 waves tile the
//   64x64 output as (ntile wv&3, row-quarter wv>>2) with full-K 32 MFMA and
//   direct store -- split-k and its barrier/partials removed.
// - Main loop identical to R23 (J=2 pairs/wave, dual-chain fast path, LPT
//   sorted perm). LDS 16*9216=147456B (1 block/CU, 16 waves/CU).
// R22 lesson: 64KB LDS does not change occupancy. R18 lesson: never pass a
// 2nd launch_bounds arg. R19 lesson: keep the bpermute gather.

typedef __attribute__((ext_vector_type(8))) short short8;
typedef __attribute__((ext_vector_type(4))) float f32x4;
typedef __attribute__((ext_vector_type(2))) unsigned int u32x2;
typedef __attribute__((ext_vector_type(4))) unsigned int u32x4;
typedef __fp16 f16x2 __attribute__((ext_vector_type(2)));
typedef __fp16 f16x8 __attribute__((ext_vector_type(8)));

static __device__ __forceinline__ int rfl(int v){
    return __builtin_amdgcn_readfirstlane(v);
}
static __device__ __forceinline__ float celu1(float x){
    return x > 0.0f ? x : (__expf(x) - 1.0f);
}
static __device__ __forceinline__ unsigned int pkh(float lo, float hi){
    f16x2 t = __builtin_amdgcn_cvt_pkrtz(lo, hi);
    return __builtin_bit_cast(unsigned int, t);
}
// round-to-nearest-even f16 pack (matches previous (__fp16) casts of P)
static __device__ __forceinline__ unsigned int pkh_rte(float lo, float hi){
    unsigned short a = __builtin_bit_cast(unsigned short, (__fp16)lo);
    unsigned short b = __builtin_bit_cast(unsigned short, (__fp16)hi);
    return (unsigned int)a | ((unsigned int)b << 16);
}

// ---------------- Kernel 0: seg boundaries + W3/W2 prep (merged) -------------
// W3frag is fragment-ordered for n-tile t, K-chunk kk with the PERMUTED k':
//   k' = q*256 + r*16 + mt*4 + i   <->   k = (q*4+i)*64 + mt*16 + r
// so the agg epilogue's A-side (flush-register order) and B-side agree.
__global__ void setup_kernel(const int* __restrict__ out_index,
                             int* __restrict__ seg_start, int E, int N,
                             const float* __restrict__ W3, const float* __restrict__ W2,
                             __fp16* __restrict__ W3frag,
                             unsigned int* __restrict__ W2f16,
                             int* __restrict__ cnts)
{
    int o = blockIdx.x * blockDim.x + threadIdx.x;
    if (o == 0) { cnts[0] = 0; cnts[1] = 0; }
    if (o < E) {
        int cur = out_index[o];
        if (o == 0) {
            for (int v = 0; v <= cur; ++v) seg_start[v] = 0;
        } else {
            int prev = out_index[o - 1];
            for (int v = prev + 1; v <= cur; ++v) seg_start[v] = o;
        }
        if (o == E - 1) {
            for (int v = cur + 1; v <= N; ++v) seg_start[v] = E;
        }
    }
    if (o < 65536) {
        int j    = o & 7;
        int lane = (o >> 3) & 63;
        int t    = (o >> 9) & 3;
        int kk   = o >> 11;
        int kp = kk * 32 + (lane >> 4) * 8 + j;      // permuted k'
        int qq = kp >> 8;
        int rr = (kp >> 4) & 15;
        int mt = (kp >> 2) & 3;
        int ii = kp & 3;
        int k = (qq * 4 + ii) * 64 + mt * 16 + rr;   // true flat k = c*64 + m
        int n = t * 16 + (lane & 15);
        W3frag[o] = (__fp16)W3[k * 64 + n];
    } else if (o < 65536 + 1024) {
        int o2 = o - 65536;
        int nt   = o2 >> 8;
        int lane = (o2 >> 2) & 63;
        int d    = o2 & 3;
        int q = lane >> 4, rr = lane & 15;
        unsigned int v = 0;
        if (q < 2) {
            int k0 = q * 8 + 2 * d;
            int n = nt * 16 + rr;
            v = pkh(W2[k0 * 64 + n], W2[(k0 + 1) * 64 + n]);
        }
        W2f16[o2] = v;
    }
}

// ---------------- Kernel 0b: bucket points by step count (LPT order) ---------
// HEAVY (cnt>32, 2 K-steps) -> slots from the FRONT (blocks launch first);
// light (cnt<=32) -> slots from the back. Within-bucket order arbitrary;
// output indexed by point id, so results are deterministic regardless.
__global__ __launch_bounds__(256) void sort_kernel(
    const int* __restrict__ seg_start,
    int* __restrict__ perm, int* __restrict__ cnts, int N)
{
    __shared__ int wh[4], wo[4];
    __shared__ int baseH, baseL;
    int v = blockIdx.x * 256 + threadIdx.x;
    int lane = threadIdx.x & 63;
    int wv = threadIdx.x >> 6;
    int cnt = (v < N) ? (seg_start[v + 1] - seg_start[v]) : 0;
    bool heavy = (v < N) && (cnt > 32);
    unsigned long long m = __ballot(heavy);
    int hpref = __popcll(m & ((1ull << lane) - 1ull));   // heavies before me in wave
    int hcnt = __popcll(m);
    if (lane == 0) wh[wv] = hcnt;
    __syncthreads();
    if (threadIdx.x == 0) {
        int t = 0;
        #pragma unroll
        for (int i = 0; i < 4; ++i) { wo[i] = t; t += wh[i]; }
        int nval = N - blockIdx.x * 256; if (nval > 256) nval = 256;
        baseH = atomicAdd(&cnts[0], t);              // heavies from the front
        baseL = atomicAdd(&cnts[1], nval - t);       // lights from the back
    }
    __syncthreads();
    if (v < N) {
        if (heavy) {
            perm[baseH + wo[wv] + hpref] = v;
        } else {
            int lightsBeforeWave = wv * 64 - wo[wv];
            perm[N - 1 - (baseL + lightsBeforeWave + (lane - hpref))] = v;
        }
    }
}

// ---------------- Kernel 1: edge aggregation + fused output GEMM -------------
// Wave wv (0..15) processes pairs (blockIdx*32 + wv*2 + j), j=0,1; block owns
// 64 consecutive sorted points.
__global__ __launch_bounds__(1024) void agg_kernel(
    const float* __restrict__ x_in, const float* __restrict__ pos_in,
    const float* __restrict__ pos_out, const int* __restrict__ in_index,
    const int* __restrict__ seg_start, const int* __restrict__ perm,
    const float* __restrict__ W1,
    const unsigned int* __restrict__ W2f16, const __fp16* __restrict__ W3frag,
    const float* __restrict__ b3, float* __restrict__ out, int E)
{
    __shared__ __align__(16) unsigned char ldsraw[16 * 9216];   // 147456B
    int lane = threadIdx.x & 63;
    int wv = threadIdx.x >> 6;                 // 0..15
    unsigned char* H2L = ldsraw + wv * 9216;   // staging 0..3071; tile rows m*144
    int r = lane & 15;
    int q = lane >> 4;
    int l31 = lane & 31;
    bool hihalf = lane >= 32;
    int vq = 32 * q;                           // byte-addr component for bpermute

    // zero block for padded-K A-frag lanes (bytes 9200..9215 never written)
    if (lane == 0) *(u32x4*)(H2L + 9200) = (u32x4){0u, 0u, 0u, 0u};

    // W2 B-frags (constant)
    f16x8 bfr[4];
    #pragma unroll
    for (int nt = 0; nt < 4; ++nt)
        bfr[nt] = __builtin_bit_cast(f16x8, *((const u32x4*)W2f16 + nt * 64 + lane));

    // W1 columns (uniform -> SGPRs)
    float w1a[16], w1b[16], w1c[16];
    #pragma unroll
    for (int c = 0; c < 16; ++c) { w1a[c] = W1[c]; w1b[c] = W1[16 + c]; w1c[c] = W1[32 + c]; }

    // packed f16 products for the wave's 4 points (named regs, static access)
    u32x4 pA0l, pA0h, pA1l, pA1h, pB0l, pB0h, pB1l, pB1h;

    // ---- prologue loader for pair pj: issues the 4-deep dependent chain ----
    auto prologue = [&](int pj, int& idxs, float& pox, float& poy, float& poz,
                        float& pi0, float& pi1, float& pi2) {
        int pw = blockIdx.x * 32 + wv * 2 + pj;
        int pid0 = rfl(perm[pw * 2]);
        int pid1 = rfl(perm[pw * 2 + 1]);
        int sg0 = rfl(seg_start[pid0]);
        int se0 = rfl(seg_start[pid0 + 1]);
        int sg1 = rfl(seg_start[pid1]);
        int cf0 = se0 - sg0;
        int cc0 = cf0 > 64 ? 64 : cf0;
        int nA = pid0, ebA = sg0;
        int nB, ebB;
        if (cc0 > 32) { nB = pid0; ebB = sg0 + 32; }
        else          { nB = pid1; ebB = sg1; }
        int nH = hihalf ? nB : nA;
        int ebH = hihalf ? ebB : ebA;
        int i0 = ebH + l31; i0 = i0 < E ? i0 : E - 1;
        idxs = in_index[i0];
        pox = pos_out[nH * 3 + 0];
        poy = pos_out[nH * 3 + 1];
        poz = pos_out[nH * 3 + 2];
        pi0 = pos_in[idxs * 3 + 0];
        pi1 = pos_in[idxs * 3 + 1];
        pi2 = pos_in[idxs * 3 + 2];
    };

    // ---- shared phase helpers (fast path) ----
    // gather: bpermute(idxs) -> x_in -> packed A-frags for both halves
    auto gather = [&](int idxs, int rem0, int rem1, f16x8* ax) {
        #pragma unroll
        for (int h = 0; h < 2; ++h) {
            int remS = h ? rem1 : rem0;
            float xv[8];
            #pragma unroll
            for (int jj = 0; jj < 8; ++jj) {
                int s = __builtin_amdgcn_ds_bpermute(128 * h + vq + 4 * jj, idxs);
                float x = x_in[s * 16 + r];
                xv[jj] = ((8 * q + jj) < remS) ? x : 0.0f;
            }
            u32x4 t;
            #pragma unroll
            for (int d = 0; d < 4; ++d) t[d] = pkh(xv[2 * d], xv[2 * d + 1]);
            ax[h] = __builtin_bit_cast(f16x8, t);
        }
    };
    // h1 compute only (VALU; no LDS) -> hp[8]
    auto h1comp = [&](float pox, float poy, float poz,
                      float pi0, float pi1, float pi2, unsigned int* hp) {
        float d0 = pi0 - pox;
        float d1 = pi1 - poy;
        float d2 = pi2 - poz;
        #pragma unroll
        for (int cp = 0; cp < 8; ++cp) {
            float a0 = celu1(fmaf(d0, w1a[2 * cp],     fmaf(d1, w1b[2 * cp],     d2 * w1c[2 * cp])));
            float a1 = celu1(fmaf(d0, w1a[2 * cp + 1], fmaf(d1, w1b[2 * cp + 1], d2 * w1c[2 * cp + 1])));
            hp[cp] = pkh(a0, a1);
        }
    };
    // stage hp -> read af frags
    auto stage_af = [&](const unsigned int* hp, f16x8* af) {
        *(u32x4*)(H2L + lane * 48)      = (u32x4){hp[0], hp[1], hp[2], hp[3]};
        *(u32x4*)(H2L + lane * 48 + 16) = (u32x4){hp[4], hp[5], hp[6], hp[7]};
        #pragma unroll
        for (int et = 0; et < 4; ++et) {
            int abase = (q < 2) ? ((et * 16 + r) * 48 + q * 16) : 9200;
            af[et] = __builtin_bit_cast(f16x8, *(const u32x4*)(H2L + abase));
        }
    };
    // h2 = celu(h1 @ W2) MFMA + tile write
    auto h2tile = [&](const f16x8* af) {
        #pragma unroll
        for (int pp = 0; pp < 2; ++pp) {
            f32x4 D[4][2];
            #pragma unroll
            for (int et = 0; et < 4; ++et)
                #pragma unroll
                for (int j = 0; j < 2; ++j)
                    D[et][j] = __builtin_amdgcn_mfma_f32_16x16x32_f16(
                        af[et], bfr[2 * pp + j], (f32x4){0.f, 0.f, 0.f, 0.f}, 0, 0, 0);
            #pragma unroll
            for (int et = 0; et < 4; ++et)
                #pragma unroll
                for (int j = 0; j < 2; ++j) {
                    int nt = 2 * pp + j;
                    float v0 = celu1(D[et][j][0]);
                    float v1 = celu1(D[et][j][1]);
                    float v2 = celu1(D[et][j][2]);
                    float v3 = celu1(D[et][j][3]);
                    *(u32x2*)(H2L + (nt * 16 + r) * 144 + et * 32 + q * 8) =
                        (u32x2){pkh(v0, v1), pkh(v2, v3)};
                }
        }
    };
    // P accumulation for a 1-batch pair: half 0 -> point0, half 1 -> point1
    auto pacc = [&](const f16x8* ax, float inv0, float inv1,
                    u32x4& P0l, u32x4& P0h, u32x4& P1l, u32x4& P1h) {
        f32x4 C0[4], C1[4];
        #pragma unroll
        for (int mt = 0; mt < 4; ++mt) {
            f16x8 b0 = __builtin_bit_cast(f16x8,
                *(u32x4*)(H2L + (mt * 16 + r) * 144 + q * 16));
            f16x8 b1 = __builtin_bit_cast(f16x8,
                *(u32x4*)(H2L + (mt * 16 + r) * 144 + 64 + q * 16));
            C0[mt] = __builtin_amdgcn_mfma_f32_16x16x32_f16(ax[0], b0, (f32x4){0.f,0.f,0.f,0.f}, 0, 0, 0);
            C1[mt] = __builtin_amdgcn_mfma_f32_16x16x32_f16(ax[1], b1, (f32x4){0.f,0.f,0.f,0.f}, 0, 0, 0);
        }
        P0l = (u32x4){pkh_rte(C0[0][0]*inv0, C0[0][1]*inv0), pkh_rte(C0[0][2]*inv0, C0[0][3]*inv0),
                      pkh_rte(C0[1][0]*inv0, C0[1][1]*inv0), pkh_rte(C0[1][2]*inv0, C0[1][3]*inv0)};
        P0h = (u32x4){pkh_rte(C0[2][0]*inv0, C0[2][1]*inv0), pkh_rte(C0[2][2]*inv0, C0[2][3]*inv0),
                      pkh_rte(C0[3][0]*inv0, C0[3][1]*inv0), pkh_rte(C0[3][2]*inv0, C0[3][3]*inv0)};
        P1l = (u32x4){pkh_rte(C1[0][0]*inv1, C1[0][1]*inv1), pkh_rte(C1[0][2]*inv1, C1[0][3]*inv1),
                      pkh_rte(C1[1][0]*inv1, C1[1][1]*inv1), pkh_rte(C1[1][2]*inv1, C1[1][3]*inv1)};
        P1h = (u32x4){pkh_rte(C1[2][0]*inv1, C1[2][1]*inv1), pkh_rte(C1[2][2]*inv1, C1[2][3]*inv1),
                      pkh_rte(C1[3][0]*inv1, C1[3][1]*inv1), pkh_rte(C1[3][2]*inv1, C1[3][3]*inv1)};
    };

    // ---- generic per-pair pipeline (heavy waves) ----
    auto run_pair = [&](int pj, int idxs, float pox, float poy, float poz,
                        float pi0, float pi1, float pi2,
                        u32x4& P0l, u32x4& P0h, u32x4& P1l, u32x4& P1h) {
        int pw = blockIdx.x * 32 + wv * 2 + pj;
        int pid[2], sg[2], cf[2], cc[2], p[3];
        pid[0] = rfl(perm[pw * 2]);
        pid[1] = rfl(perm[pw * 2 + 1]);
        p[0] = 0;
        #pragma unroll
        for (int i = 0; i < 2; ++i) {
            sg[i] = rfl(seg_start[pid[i]]);
            int se = rfl(seg_start[pid[i] + 1]);
            cf[i] = se - sg[i];
            cc[i] = cf[i] > 64 ? 64 : cf[i];
            p[i + 1] = p[i] + (cc[i] > 32 ? 2 : 1);
        }
        int ns = p[2];                         // total 32-slot steps, 2..4

        #define STEP_DESC(t, nS, cfS, remS, ebS)                         \
            {                                                            \
                int i_ = 0, pi_ = 0;                                     \
                if ((t) >= p[1]) { i_ = 1; pi_ = p[1]; }                 \
                int cf_ = cf[0], cc_ = cc[0], sg_ = sg[0], id_ = pid[0]; \
                if (i_ >= 1) { cf_ = cf[1]; cc_ = cc[1]; sg_ = sg[1]; id_ = pid[1]; } \
                int kb_ = ((t) - pi_) * 32;                              \
                (nS) = id_; (cfS) = cf_;                                 \
                (remS) = cc_ - kb_; (ebS) = sg_ + kb_;                   \
            }

        f32x4 C[4];
        #pragma unroll
        for (int mt = 0; mt < 4; ++mt) C[mt] = (f32x4){0.f, 0.f, 0.f, 0.f};
        int cur_n = pid[0];
        int cur_cf = cf[0];

        int nA, cfA, remA, ebA, nB, cfB, remB, ebB;
        STEP_DESC(0, nA, cfA, remA, ebA)
        STEP_DESC(1, nB, cfB, remB, ebB)

        #pragma unroll 1
        for (int b = 0; b < 2; ++b) {
            if (2 * b >= ns) break;
            bool more = (2 * b + 2) < ns;      // wave-uniform

            int nA2 = 0, cfA2 = 0, remA2 = 0, ebA2 = 0;
            int nB2 = 0, cfB2 = 0, remB2 = 0, ebB2 = 0;
            int idxs_next = 0;
            float pox2 = 0.f, poy2 = 0.f, poz2 = 0.f;
            if (more) {
                STEP_DESC(2 * b + 2, nA2, cfA2, remA2, ebA2)
                STEP_DESC(2 * b + 3, nB2, cfB2, remB2, ebB2)
                int nH2 = hihalf ? nB2 : nA2;
                int ebH2 = hihalf ? ebB2 : ebA2;
                int idx2 = ebH2 + l31; idx2 = idx2 < E ? idx2 : E - 1;
                idxs_next = in_index[idx2];
                pox2 = pos_out[nH2 * 3 + 0];
                poy2 = pos_out[nH2 * 3 + 1];
                poz2 = pos_out[nH2 * 3 + 2];
            }

            f16x8 ax[2];
            gather(idxs, remA, remB, ax);

            unsigned int hp[8];
            h1comp(pox, poy, poz, pi0, pi1, pi2, hp);
            f16x8 af[4];
            stage_af(hp, af);
            h2tile(af);

            float pi0n = 0.f, pi1n = 0.f, pi2n = 0.f;
            if (more) {
                pi0n = pos_in[idxs_next * 3 + 0];
                pi1n = pos_in[idxs_next * 3 + 1];
                pi2n = pos_in[idxs_next * 3 + 2];
            }

            // P accumulation per half, flush to registers on transitions
            #pragma unroll
            for (int h = 0; h < 2; ++h) {
                int nS  = h ? nB : nA;
                int cfS = h ? cfB : cfA;
                if (rfl(nS) != cur_n) {
                    float inv = cur_cf > 0 ? 1.0f / (float)cur_cf : 0.0f;
                    P0l = (u32x4){pkh_rte(C[0][0] * inv, C[0][1] * inv),
                                  pkh_rte(C[0][2] * inv, C[0][3] * inv),
                                  pkh_rte(C[1][0] * inv, C[1][1] * inv),
                                  pkh_rte(C[1][2] * inv, C[1][3] * inv)};
                    P0h = (u32x4){pkh_rte(C[2][0] * inv, C[2][1] * inv),
                                  pkh_rte(C[2][2] * inv, C[2][3] * inv),
                                  pkh_rte(C[3][0] * inv, C[3][1] * inv),
                                  pkh_rte(C[3][2] * inv, C[3][3] * inv)};
                    #pragma unroll
                    for (int mt = 0; mt < 4; ++mt) C[mt] = (f32x4){0.f, 0.f, 0.f, 0.f};
                    cur_n = nS; cur_cf = cfS;
                }
                #pragma unroll
                for (int mt = 0; mt < 4; ++mt) {
                    f16x8 bb = __builtin_bit_cast(f16x8,
                        *(u32x4*)(H2L + (mt * 16 + r) * 144 + h * 64 + q * 16));
                    C[mt] = __builtin_amdgcn_mfma_f32_16x16x32_f16(ax[h], bb, C[mt], 0, 0, 0);
                }
            }

            if (more) {
                nA = nA2; cfA = cfA2; remA = remA2; ebA = ebA2;
                nB = nB2; cfB = cfB2; remB = remB2; ebB = ebB2;
                idxs = idxs_next;
                pox = pox2; poy = poy2; poz = poz2;
                pi0 = pi0n; pi1 = pi1n; pi2 = pi2n;
            }
        }

        // final flush (always the pair's second point -> slot 1)
        {
            float inv = cur_cf > 0 ? 1.0f / (float)cur_cf : 0.0f;
            P1l = (u32x4){pkh_rte(C[0][0] * inv, C[0][1] * inv),
                          pkh_rte(C[0][2] * inv, C[0][3] * inv),
                          pkh_rte(C[1][0] * inv, C[1][1] * inv),
                          pkh_rte(C[1][2] * inv, C[1][3] * inv)};
            P1h = (u32x4){pkh_rte(C[2][0] * inv, C[2][1] * inv),
                          pkh_rte(C[2][2] * inv, C[2][3] * inv),
                          pkh_rte(C[3][0] * inv, C[3][1] * inv),
                          pkh_rte(C[3][2] * inv, C[3][3] * inv)};
        }
        #undef STEP_DESC
    };

    // ---- wave-uniform descriptors for both pairs (cheap scalar loads) ----
    int pwb = blockIdx.x * 32 + wv * 2;
    int pA0 = rfl(perm[pwb * 2]);
    int pA1 = rfl(perm[pwb * 2 + 1]);
    int pB0 = rfl(perm[pwb * 2 + 2]);
    int pB1 = rfl(perm[pwb * 2 + 3]);
    int cfA0v = rfl(seg_start[pA0 + 1]) - rfl(seg_start[pA0]);
    int cfA1v = rfl(seg_start[pA1 + 1]) - rfl(seg_start[pA1]);
    int cfB0v = rfl(seg_start[pB0 + 1]) - rfl(seg_start[pB0]);
    int cfB1v = rfl(seg_start[pB1 + 1]) - rfl(seg_start[pB1]);
    bool fastw = (cfA0v <= 32) && (cfA1v <= 32) && (cfB0v <= 32) && (cfB1v <= 32);

    // issue BOTH pairs' prologue chains up front
    int ix0, ix1;
    float pox0, poy0, poz0, pi00, pi01, pi02;
    float pox1, poy1, poz1, pi10, pi11, pi12;
    prologue(0, ix0, pox0, poy0, poz0, pi00, pi01, pi02);
    prologue(1, ix1, pox1, poy1, poz1, pi10, pi11, pi12);

    if (fastw) {
        // ===== FAST PATH: all 4 points light; dual independent chains =====
        float invA0 = cfA0v > 0 ? 1.0f / (float)cfA0v : 0.0f;
        float invA1 = cfA1v > 0 ? 1.0f / (float)cfA1v : 0.0f;
        float invB0 = cfB0v > 0 ? 1.0f / (float)cfB0v : 0.0f;
        float invB1 = cfB1v > 0 ? 1.0f / (float)cfB1v : 0.0f;

        // all VMEM for both chains issued first
        f16x8 ax0[2], ax1[2];
        gather(ix0, cfA0v, cfA1v, ax0);
        gather(ix1, cfB0v, cfB1v, ax1);

        // chain0 h1; chain1 h1 compute overlaps chain0's LDS/MFMA phases
        unsigned int hp0[8], hp1[8];
        h1comp(pox0, poy0, poz0, pi00, pi01, pi02, hp0);
        f16x8 af0[4];
        stage_af(hp0, af0);
        h1comp(pox1, poy1, poz1, pi10, pi11, pi12, hp1);   // VALU under LDS latency

        h2tile(af0);
        pacc(ax0, invA0, invA1, pA0l, pA0h, pA1l, pA1h);

        f16x8 af1[4];
        stage_af(hp1, af1);    // ds-writes ordered after chain0's bb reads
        h2tile(af1);
        pacc(ax1, invB0, invB1, pB0l, pB0h, pB1l, pB1h);
    } else {
        // ===== GENERIC PATH =====
        run_pair(0, ix0, pox0, poy0, poz0, pi00, pi01, pi02, pA0l, pA0h, pA1l, pA1h);
        run_pair(1, ix1, pox1, poy1, poz1, pi10, pi11, pi12, pB0l, pB0h, pB1l, pB1h);
    }

    // ================= fused output GEMM (64-point M-tile) =================
    // A-tile: rows 0..63 = block-local points, 1024 f16 in k' order, 2048B/row,
    // 16B chunks XOR-swizzled by ((row&7)<<4). Overlays the staging region
    // (131072B <= 147456B).
    __syncthreads();   // all waves done with H2L staging
    {
        auto storeP = [&](int row, u32x4 lo, u32x4 hi) {
            unsigned int base = (unsigned int)(row * 2048 + q * 512 + r * 32);
            unsigned int swz = (unsigned int)((row & 7) << 4);
            *(u32x4*)(ldsraw + (base ^ swz)) = lo;
            *(u32x4*)(ldsraw + ((base + 16u) ^ swz)) = hi;
        };
        int row0 = wv * 4;
        storeP(row0 + 0, pA0l, pA0h);
        storeP(row0 + 1, pA1l, pA1h);
        storeP(row0 + 2, pB0l, pB0h);
        storeP(row0 + 3, pB1l, pB1h);
    }
    __syncthreads();
    {
        // wave wv: ntile nt = wv&3 (cols nt*16..+16), row-quarter rq = wv>>2
        // (rows rq*16..+16), full K (32 kk). Same-nt waves share B via L1/L2.
        int nt = wv & 3;
        int rq = wv >> 2;
        const short8* Bp = (const short8*)W3frag + nt * 64 + lane;
        f32x4 Cg = (f32x4){0.f, 0.f, 0.f, 0.f};
        unsigned int ab = (unsigned int)((rq * 16 + r) * 2048 + q * 16);
        unsigned int aswz = (unsigned int)((r & 7) << 4);
        #pragma unroll
        for (int kk = 0; kk < 32; ++kk) {
            f16x8 bf = __builtin_bit_cast(f16x8, Bp[kk * 256]);   // frag (kk*4 + nt)
            f16x8 a  = __builtin_bit_cast(f16x8,
                *(const u32x4*)(ldsraw + ((ab + (unsigned int)(kk * 64)) ^ aswz)));
            Cg = __builtin_amdgcn_mfma_f32_16x16x32_f16(a, bf, Cg, 0, 0, 0);
        }
        int colbase = nt * 16 + r;
        float bias = b3[colbase];
        #pragma unroll
        for (int i = 0; i < 4; ++i) {
            int prow = perm[blockIdx.x * 64 + rq * 16 + q * 4 + i];
            out[(size_t)prow * 64 + colbase] = Cg[i] + bias;
        }
    }
}

extern "C" void kernel_launch(void* const* d_in, const int* in_sizes, int n_in,
                              void* d_out, int out_size, void* d_ws, size_t ws_size,
                              hipStream_t stream)
{
    const float* x_in    = (const float*)d_in[0];
    const float* pos_in  = (const float*)d_in[1];
    const float* pos_out = (const float*)d_in[2];
    const int* in_index  = (const int*)d_in[3];
    const int* out_index = (const int*)d_in[4];
    const float* W1 = (const float*)d_in[5];
    const float* W2 = (const float*)d_in[6];
    const float* W3 = (const float*)d_in[7];
    const float* b3 = (const float*)d_in[8];

    int N = in_sizes[0] / 16;    // 32768
    int E = in_sizes[3];         // 786432
    float* out = (float*)d_out;

    // workspace: seg (N+1) | W3frag (128KB) | W2f16 (4KB) | perm (N) | cnts (2)
    char* ws = (char*)d_ws;
    int* seg = (int*)ws;
    size_t off = (((size_t)(N + 1) * 4 + 255) & ~(size_t)255);
    __fp16* W3frag = (__fp16*)(ws + off);
    off += (size_t)65536 * 2;
    unsigned int* W2f16 = (unsigned int*)(ws + off);
    off += (size_t)1024 * 4;
    int* perm = (int*)(ws + off);
    off += (size_t)N * 4;
    int* cnts = (int*)(ws + off);

    setup_kernel<<<(E + 255) / 256, 256, 0, stream>>>(out_index, seg, E, N,
                                                      W3, W2, W3frag, W2f16, cnts);
    sort_kernel<<<(N + 255) / 256, 256, 0, stream>>>(seg, perm, cnts, N);
    agg_kernel<<<N / 64, 1024, 0, stream>>>(x_in, pos_in, pos_out, in_index, seg,
                                            perm, W1, W2f16, W3frag, b3, out, E);
}

// Round 16
// 131.115 us; speedup vs baseline: 1.1328x; 1.1328x over previous
//
#include <hip/hip_runtime.h>
#include <hip/hip_bf16.h>

// PointConv: N=32768 points, E=786432 edges (sorted by out_index), K<=64
// product[n][c][m] = inv_n * sum_edges x_in[src][c] * celu(celu(pos_local@W1)@W2)[m]
// out[n][k] = product[n].flat(1024) @ W3[1024][64] + b3[k]
//
// R26 = R23 exact (best verified: 132.15us total; agg 55.4us). R25's crash
// was a grid-size transcription error (N/16 -> 2048 blocks -> perm OOB);
// correct launch is N/32 = 1024 blocks for 32 pts/block.
// 8 waves x J=2 pairs, 32 pts/block, dual-chain fast path, split-k epilogue,
// LPT sort (heavies first), 73728B LDS, __launch_bounds__(512).
// Ledger: R18/R24 register-wall (2nd launch_bounds arg or 1024-thr -> 64
// VGPR spill); R19 keep bpermute gather; R22 LDS size doesn't move occupancy.

typedef __attribute__((ext_vector_type(8))) short short8;
typedef __attribute__((ext_vector_type(4))) float f32x4;
typedef __attribute__((ext_vector_type(2))) unsigned int u32x2;
typedef __attribute__((ext_vector_type(4))) unsigned int u32x4;
typedef __fp16 f16x2 __attribute__((ext_vector_type(2)));
typedef __fp16 f16x8 __attribute__((ext_vector_type(8)));

static __device__ __forceinline__ int rfl(int v){
    return __builtin_amdgcn_readfirstlane(v);
}
static __device__ __forceinline__ float celu1(float x){
    return x > 0.0f ? x : (__expf(x) - 1.0f);
}
static __device__ __forceinline__ unsigned int pkh(float lo, float hi){
    f16x2 t = __builtin_amdgcn_cvt_pkrtz(lo, hi);
    return __builtin_bit_cast(unsigned int, t);
}
// round-to-nearest-even f16 pack (matches previous (__fp16) casts of P)
static __device__ __forceinline__ unsigned int pkh_rte(float lo, float hi){
    unsigned short a = __builtin_bit_cast(unsigned short, (__fp16)lo);
    unsigned short b = __builtin_bit_cast(unsigned short, (__fp16)hi);
    return (unsigned int)a | ((unsigned int)b << 16);
}

// ---------------- Kernel 0: seg boundaries + W3/W2 prep (merged) -------------
// W3frag is fragment-ordered for n-tile t, K-chunk kk with the PERMUTED k':
//   k' = q*256 + r*16 + mt*4 + i   <->   k = (q*4+i)*64 + mt*16 + r
// so the agg epilogue's A-side (flush-register order) and B-side agree.
__global__ void setup_kernel(const int* __restrict__ out_index,
                             int* __restrict__ seg_start, int E, int N,
                             const float* __restrict__ W3, const float* __restrict__ W2,
                             __fp16* __restrict__ W3frag,
                             unsigned int* __restrict__ W2f16,
                             int* __restrict__ cnts)
{
    int o = blockIdx.x * blockDim.x + threadIdx.x;
    if (o == 0) { cnts[0] = 0; cnts[1] = 0; }
    if (o < E) {
        int cur = out_index[o];
        if (o == 0) {
            for (int v = 0; v <= cur; ++v) seg_start[v] = 0;
        } else {
            int prev = out_index[o - 1];
            for (int v = prev + 1; v <= cur; ++v) seg_start[v] = o;
        }
        if (o == E - 1) {
            for (int v = cur + 1; v <= N; ++v) seg_start[v] = E;
        }
    }
    if (o < 65536) {
        int j    = o & 7;
        int lane = (o >> 3) & 63;
        int t    = (o >> 9) & 3;
        int kk   = o >> 11;
        int kp = kk * 32 + (lane >> 4) * 8 + j;      // permuted k'
        int qq = kp >> 8;
        int rr = (kp >> 4) & 15;
        int mt = (kp >> 2) & 3;
        int ii = kp & 3;
        int k = (qq * 4 + ii) * 64 + mt * 16 + rr;   // true flat k = c*64 + m
        int n = t * 16 + (lane & 15);
        W3frag[o] = (__fp16)W3[k * 64 + n];
    } else if (o < 65536 + 1024) {
        int o2 = o - 65536;
        int nt   = o2 >> 8;
        int lane = (o2 >> 2) & 63;
        int d    = o2 & 3;
        int q = lane >> 4, rr = lane & 15;
        unsigned int v = 0;
        if (q < 2) {
            int k0 = q * 8 + 2 * d;
            int n = nt * 16 + rr;
            v = pkh(W2[k0 * 64 + n], W2[(k0 + 1) * 64 + n]);
        }
        W2f16[o2] = v;
    }
}

// ---------------- Kernel 0b: bucket points by step count (LPT order) ---------
// HEAVY (cnt>32, 2 K-steps) -> slots from the FRONT (blocks launch first);
// light (cnt<=32) -> slots from the back. Within-bucket order arbitrary;
// output indexed by point id, so results are deterministic regardless.
__global__ __launch_bounds__(256) void sort_kernel(
    const int* __restrict__ seg_start,
    int* __restrict__ perm, int* __restrict__ cnts, int N)
{
    __shared__ int wh[4], wo[4];
    __shared__ int baseH, baseL;
    int v = blockIdx.x * 256 + threadIdx.x;
    int lane = threadIdx.x & 63;
    int wv = threadIdx.x >> 6;
    int cnt = (v < N) ? (seg_start[v + 1] - seg_start[v]) : 0;
    bool heavy = (v < N) && (cnt > 32);
    unsigned long long m = __ballot(heavy);
    int hpref = __popcll(m & ((1ull << lane) - 1ull));   // heavies before me in wave
    int hcnt = __popcll(m);
    if (lane == 0) wh[wv] = hcnt;
    __syncthreads();
    if (threadIdx.x == 0) {
        int t = 0;
        #pragma unroll
        for (int i = 0; i < 4; ++i) { wo[i] = t; t += wh[i]; }
        int nval = N - blockIdx.x * 256; if (nval > 256) nval = 256;
        baseH = atomicAdd(&cnts[0], t);              // heavies from the front
        baseL = atomicAdd(&cnts[1], nval - t);       // lights from the back
    }
    __syncthreads();
    if (v < N) {
        if (heavy) {
            perm[baseH + wo[wv] + hpref] = v;
        } else {
            int lightsBeforeWave = wv * 64 - wo[wv];
            perm[N - 1 - (baseL + lightsBeforeWave + (lane - hpref))] = v;
        }
    }
}

// ---------------- Kernel 1: edge aggregation + fused output GEMM -------------
// Wave wv (0..7) processes pairs (blockIdx*16 + wv*2 + j), j=0,1; block owns
// 32 consecutive sorted points.
__global__ __launch_bounds__(512) void agg_kernel(
    const float* __restrict__ x_in, const float* __restrict__ pos_in,
    const float* __restrict__ pos_out, const int* __restrict__ in_index,
    const int* __restrict__ seg_start, const int* __restrict__ perm,
    const float* __restrict__ W1,
    const unsigned int* __restrict__ W2f16, const __fp16* __restrict__ W3frag,
    const float* __restrict__ b3, float* __restrict__ out, int E)
{
    __shared__ __align__(16) unsigned char ldsraw[8 * 9216];
    int lane = threadIdx.x & 63;
    int wv = threadIdx.x >> 6;                 // 0..7
    unsigned char* H2L = ldsraw + wv * 9216;   // staging 0..3071; tile rows m*144
    int r = lane & 15;
    int q = lane >> 4;
    int l31 = lane & 31;
    bool hihalf = lane >= 32;
    int vq = 32 * q;                           // byte-addr component for bpermute

    // zero block for padded-K A-frag lanes (bytes 9200..9215 never written)
    if (lane == 0) *(u32x4*)(H2L + 9200) = (u32x4){0u, 0u, 0u, 0u};

    // W2 B-frags (constant)
    f16x8 bfr[4];
    #pragma unroll
    for (int nt = 0; nt < 4; ++nt)
        bfr[nt] = __builtin_bit_cast(f16x8, *((const u32x4*)W2f16 + nt * 64 + lane));

    // W1 columns (uniform -> SGPRs)
    float w1a[16], w1b[16], w1c[16];
    #pragma unroll
    for (int c = 0; c < 16; ++c) { w1a[c] = W1[c]; w1b[c] = W1[16 + c]; w1c[c] = W1[32 + c]; }

    // packed f16 products for the wave's 4 points (named regs, static access)
    u32x4 pA0l, pA0h, pA1l, pA1h, pB0l, pB0h, pB1l, pB1h;

    // ---- prologue loader for pair pj: issues the 4-deep dependent chain ----
    auto prologue = [&](int pj, int& idxs, float& pox, float& poy, float& poz,
                        float& pi0, float& pi1, float& pi2) {
        int pw = blockIdx.x * 16 + wv * 2 + pj;
        int pid0 = rfl(perm[pw * 2]);
        int pid1 = rfl(perm[pw * 2 + 1]);
        int sg0 = rfl(seg_start[pid0]);
        int se0 = rfl(seg_start[pid0 + 1]);
        int sg1 = rfl(seg_start[pid1]);
        int cf0 = se0 - sg0;
        int cc0 = cf0 > 64 ? 64 : cf0;
        int nA = pid0, ebA = sg0;
        int nB, ebB;
        if (cc0 > 32) { nB = pid0; ebB = sg0 + 32; }
        else          { nB = pid1; ebB = sg1; }
        int nH = hihalf ? nB : nA;
        int ebH = hihalf ? ebB : ebA;
        int i0 = ebH + l31; i0 = i0 < E ? i0 : E - 1;
        idxs = in_index[i0];
        pox = pos_out[nH * 3 + 0];
        poy = pos_out[nH * 3 + 1];
        poz = pos_out[nH * 3 + 2];
        pi0 = pos_in[idxs * 3 + 0];
        pi1 = pos_in[idxs * 3 + 1];
        pi2 = pos_in[idxs * 3 + 2];
    };

    // ---- shared phase helpers (fast path) ----
    // gather: bpermute(idxs) -> x_in -> packed A-frags for both halves
    auto gather = [&](int idxs, int rem0, int rem1, f16x8* ax) {
        #pragma unroll
        for (int h = 0; h < 2; ++h) {
            int remS = h ? rem1 : rem0;
            float xv[8];
            #pragma unroll
            for (int jj = 0; jj < 8; ++jj) {
                int s = __builtin_amdgcn_ds_bpermute(128 * h + vq + 4 * jj, idxs);
                float x = x_in[s * 16 + r];
                xv[jj] = ((8 * q + jj) < remS) ? x : 0.0f;
            }
            u32x4 t;
            #pragma unroll
            for (int d = 0; d < 4; ++d) t[d] = pkh(xv[2 * d], xv[2 * d + 1]);
            ax[h] = __builtin_bit_cast(f16x8, t);
        }
    };
    // h1 compute only (VALU; no LDS) -> hp[8]
    auto h1comp = [&](float pox, float poy, float poz,
                      float pi0, float pi1, float pi2, unsigned int* hp) {
        float d0 = pi0 - pox;
        float d1 = pi1 - poy;
        float d2 = pi2 - poz;
        #pragma unroll
        for (int cp = 0; cp < 8; ++cp) {
            float a0 = celu1(fmaf(d0, w1a[2 * cp],     fmaf(d1, w1b[2 * cp],     d2 * w1c[2 * cp])));
            float a1 = celu1(fmaf(d0, w1a[2 * cp + 1], fmaf(d1, w1b[2 * cp + 1], d2 * w1c[2 * cp + 1])));
            hp[cp] = pkh(a0, a1);
        }
    };
    // stage hp -> read af frags
    auto stage_af = [&](const unsigned int* hp, f16x8* af) {
        *(u32x4*)(H2L + lane * 48)      = (u32x4){hp[0], hp[1], hp[2], hp[3]};
        *(u32x4*)(H2L + lane * 48 + 16) = (u32x4){hp[4], hp[5], hp[6], hp[7]};
        #pragma unroll
        for (int et = 0; et < 4; ++et) {
            int abase = (q < 2) ? ((et * 16 + r) * 48 + q * 16) : 9200;
            af[et] = __builtin_bit_cast(f16x8, *(const u32x4*)(H2L + abase));
        }
    };
    // h2 = celu(h1 @ W2) MFMA + tile write
    auto h2tile = [&](const f16x8* af) {
        #pragma unroll
        for (int pp = 0; pp < 2; ++pp) {
            f32x4 D[4][2];
            #pragma unroll
            for (int et = 0; et < 4; ++et)
                #pragma unroll
                for (int j = 0; j < 2; ++j)
                    D[et][j] = __builtin_amdgcn_mfma_f32_16x16x32_f16(
                        af[et], bfr[2 * pp + j], (f32x4){0.f, 0.f, 0.f, 0.f}, 0, 0, 0);
            #pragma unroll
            for (int et = 0; et < 4; ++et)
                #pragma unroll
                for (int j = 0; j < 2; ++j) {
                    int nt = 2 * pp + j;
                    float v0 = celu1(D[et][j][0]);
                    float v1 = celu1(D[et][j][1]);
                    float v2 = celu1(D[et][j][2]);
                    float v3 = celu1(D[et][j][3]);
                    *(u32x2*)(H2L + (nt * 16 + r) * 144 + et * 32 + q * 8) =
                        (u32x2){pkh(v0, v1), pkh(v2, v3)};
                }
        }
    };
    // P accumulation for a 1-batch pair: half 0 -> point0, half 1 -> point1
    auto pacc = [&](const f16x8* ax, float inv0, float inv1,
                    u32x4& P0l, u32x4& P0h, u32x4& P1l, u32x4& P1h) {
        f32x4 C0[4], C1[4];
        #pragma unroll
        for (int mt = 0; mt < 4; ++mt) {
            f16x8 b0 = __builtin_bit_cast(f16x8,
                *(u32x4*)(H2L + (mt * 16 + r) * 144 + q * 16));
            f16x8 b1 = __builtin_bit_cast(f16x8,
                *(u32x4*)(H2L + (mt * 16 + r) * 144 + 64 + q * 16));
            C0[mt] = __builtin_amdgcn_mfma_f32_16x16x32_f16(ax[0], b0, (f32x4){0.f,0.f,0.f,0.f}, 0, 0, 0);
            C1[mt] = __builtin_amdgcn_mfma_f32_16x16x32_f16(ax[1], b1, (f32x4){0.f,0.f,0.f,0.f}, 0, 0, 0);
        }
        P0l = (u32x4){pkh_rte(C0[0][0]*inv0, C0[0][1]*inv0), pkh_rte(C0[0][2]*inv0, C0[0][3]*inv0),
                      pkh_rte(C0[1][0]*inv0, C0[1][1]*inv0), pkh_rte(C0[1][2]*inv0, C0[1][3]*inv0)};
        P0h = (u32x4){pkh_rte(C0[2][0]*inv0, C0[2][1]*inv0), pkh_rte(C0[2][2]*inv0, C0[2][3]*inv0),
                      pkh_rte(C0[3][0]*inv0, C0[3][1]*inv0), pkh_rte(C0[3][2]*inv0, C0[3][3]*inv0)};
        P1l = (u32x4){pkh_rte(C1[0][0]*inv1, C1[0][1]*inv1), pkh_rte(C1[0][2]*inv1, C1[0][3]*inv1),
                      pkh_rte(C1[1][0]*inv1, C1[1][1]*inv1), pkh_rte(C1[1][2]*inv1, C1[1][3]*inv1)};
        P1h = (u32x4){pkh_rte(C1[2][0]*inv1, C1[2][1]*inv1), pkh_rte(C1[2][2]*inv1, C1[2][3]*inv1),
                      pkh_rte(C1[3][0]*inv1, C1[3][1]*inv1), pkh_rte(C1[3][2]*inv1, C1[3][3]*inv1)};
    };

    // ---- generic per-pair pipeline (R20 path, used for heavy waves) ----
    auto run_pair = [&](int pj, int idxs, float pox, float poy, float poz,
                        float pi0, float pi1, float pi2,
                        u32x4& P0l, u32x4& P0h, u32x4& P1l, u32x4& P1h) {
        int pw = blockIdx.x * 16 + wv * 2 + pj;
        int pid[2], sg[2], cf[2], cc[2], p[3];
        pid[0] = rfl(perm[pw * 2]);
        pid[1] = rfl(perm[pw * 2 + 1]);
        p[0] = 0;
        #pragma unroll
        for (int i = 0; i < 2; ++i) {
            sg[i] = rfl(seg_start[pid[i]]);
            int se = rfl(seg_start[pid[i] + 1]);
            cf[i] = se - sg[i];
            cc[i] = cf[i] > 64 ? 64 : cf[i];
            p[i + 1] = p[i] + (cc[i] > 32 ? 2 : 1);
        }
        int ns = p[2];                         // total 32-slot steps, 2..4

        #define STEP_DESC(t, nS, cfS, remS, ebS)                         \
            {                                                            \
                int i_ = 0, pi_ = 0;                                     \
                if ((t) >= p[1]) { i_ = 1; pi_ = p[1]; }                 \
                int cf_ = cf[0], cc_ = cc[0], sg_ = sg[0], id_ = pid[0]; \
                if (i_ >= 1) { cf_ = cf[1]; cc_ = cc[1]; sg_ = sg[1]; id_ = pid[1]; } \
                int kb_ = ((t) - pi_) * 32;                              \
                (nS) = id_; (cfS) = cf_;                                 \
                (remS) = cc_ - kb_; (ebS) = sg_ + kb_;                   \
            }

        f32x4 C[4];
        #pragma unroll
        for (int mt = 0; mt < 4; ++mt) C[mt] = (f32x4){0.f, 0.f, 0.f, 0.f};
        int cur_n = pid[0];
        int cur_cf = cf[0];

        int nA, cfA, remA, ebA, nB, cfB, remB, ebB;
        STEP_DESC(0, nA, cfA, remA, ebA)
        STEP_DESC(1, nB, cfB, remB, ebB)

        #pragma unroll 1
        for (int b = 0; b < 2; ++b) {
            if (2 * b >= ns) break;
            bool more = (2 * b + 2) < ns;      // wave-uniform

            int nA2 = 0, cfA2 = 0, remA2 = 0, ebA2 = 0;
            int nB2 = 0, cfB2 = 0, remB2 = 0, ebB2 = 0;
            int idxs_next = 0;
            float pox2 = 0.f, poy2 = 0.f, poz2 = 0.f;
            if (more) {
                STEP_DESC(2 * b + 2, nA2, cfA2, remA2, ebA2)
                STEP_DESC(2 * b + 3, nB2, cfB2, remB2, ebB2)
                int nH2 = hihalf ? nB2 : nA2;
                int ebH2 = hihalf ? ebB2 : ebA2;
                int idx2 = ebH2 + l31; idx2 = idx2 < E ? idx2 : E - 1;
                idxs_next = in_index[idx2];
                pox2 = pos_out[nH2 * 3 + 0];
                poy2 = pos_out[nH2 * 3 + 1];
                poz2 = pos_out[nH2 * 3 + 2];
            }

            f16x8 ax[2];
            gather(idxs, remA, remB, ax);

            unsigned int hp[8];
            h1comp(pox, poy, poz, pi0, pi1, pi2, hp);
            f16x8 af[4];
            stage_af(hp, af);
            h2tile(af);

            float pi0n = 0.f, pi1n = 0.f, pi2n = 0.f;
            if (more) {
                pi0n = pos_in[idxs_next * 3 + 0];
                pi1n = pos_in[idxs_next * 3 + 1];
                pi2n = pos_in[idxs_next * 3 + 2];
            }

            // P accumulation per half, flush to registers on transitions
            #pragma unroll
            for (int h = 0; h < 2; ++h) {
                int nS  = h ? nB : nA;
                int cfS = h ? cfB : cfA;
                if (rfl(nS) != cur_n) {
                    float inv = cur_cf > 0 ? 1.0f / (float)cur_cf : 0.0f;
                    P0l = (u32x4){pkh_rte(C[0][0] * inv, C[0][1] * inv),
                                  pkh_rte(C[0][2] * inv, C[0][3] * inv),
                                  pkh_rte(C[1][0] * inv, C[1][1] * inv),
                                  pkh_rte(C[1][2] * inv, C[1][3] * inv)};
                    P0h = (u32x4){pkh_rte(C[2][0] * inv, C[2][1] * inv),
                                  pkh_rte(C[2][2] * inv, C[2][3] * inv),
                                  pkh_rte(C[3][0] * inv, C[3][1] * inv),
                                  pkh_rte(C[3][2] * inv, C[3][3] * inv)};
                    #pragma unroll
                    for (int mt = 0; mt < 4; ++mt) C[mt] = (f32x4){0.f, 0.f, 0.f, 0.f};
                    cur_n = nS; cur_cf = cfS;
                }
                #pragma unroll
                for (int mt = 0; mt < 4; ++mt) {
                    f16x8 bb = __builtin_bit_cast(f16x8,
                        *(u32x4*)(H2L + (mt * 16 + r) * 144 + h * 64 + q * 16));
                    C[mt] = __builtin_amdgcn_mfma_f32_16x16x32_f16(ax[h], bb, C[mt], 0, 0, 0);
                }
            }

            if (more) {
                nA = nA2; cfA = cfA2; remA = remA2; ebA = ebA2;
                nB = nB2; cfB = cfB2; remB = remB2; ebB = ebB2;
                idxs = idxs_next;
                pox = pox2; poy = poy2; poz = poz2;
                pi0 = pi0n; pi1 = pi1n; pi2 = pi2n;
            }
        }

        // final flush (always the pair's second point -> slot 1)
        {
            float inv = cur_cf > 0 ? 1.0f / (float)cur_cf : 0.0f;
            P1l = (u32x4){pkh_rte(C[0][0] * inv, C[0][1] * inv),
                          pkh_rte(C[0][2] * inv, C[0][3] * inv),
                          pkh_rte(C[1][0] * inv, C[1][1] * inv),
                          pkh_rte(C[1][2] * inv, C[1][3] * inv)};
            P1h = (u32x4){pkh_rte(C[2][0] * inv, C[2][1] * inv),
                          pkh_rte(C[2][2] * inv, C[2][3] * inv),
                          pkh_rte(C[3][0] * inv, C[3][1] * inv),
                          pkh_rte(C[3][2] * inv, C[3][3] * inv)};
        }
        #undef STEP_DESC
    };

    // ---- wave-uniform descriptors for both pairs (cheap scalar loads) ----
    int pwb = blockIdx.x * 16 + wv * 2;
    int pA0 = rfl(perm[pwb * 2]);
    int pA1 = rfl(perm[pwb * 2 + 1]);
    int pB0 = rfl(perm[pwb * 2 + 2]);
    int pB1 = rfl(perm[pwb * 2 + 3]);
    int cfA0v = rfl(seg_start[pA0 + 1]) - rfl(seg_start[pA0]);
    int cfA1v = rfl(seg_start[pA1 + 1]) - rfl(seg_start[pA1]);
    int cfB0v = rfl(seg_start[pB0 + 1]) - rfl(seg_start[pB0]);
    int cfB1v = rfl(seg_start[pB1 + 1]) - rfl(seg_start[pB1]);
    bool fastw = (cfA0v <= 32) && (cfA1v <= 32) && (cfB0v <= 32) && (cfB1v <= 32);

    // issue BOTH pairs' prologue chains up front
    int ix0, ix1;
    float pox0, poy0, poz0, pi00, pi01, pi02;
    float pox1, poy1, poz1, pi10, pi11, pi12;
    prologue(0, ix0, pox0, poy0, poz0, pi00, pi01, pi02);
    prologue(1, ix1, pox1, poy1, poz1, pi10, pi11, pi12);

    if (fastw) {
        // ===== FAST PATH: all 4 points light; dual independent chains =====
        float invA0 = cfA0v > 0 ? 1.0f / (float)cfA0v : 0.0f;
        float invA1 = cfA1v > 0 ? 1.0f / (float)cfA1v : 0.0f;
        float invB0 = cfB0v > 0 ? 1.0f / (float)cfB0v : 0.0f;
        float invB1 = cfB1v > 0 ? 1.0f / (float)cfB1v : 0.0f;

        // all VMEM for both chains issued first
        f16x8 ax0[2], ax1[2];
        gather(ix0, cfA0v, cfA1v, ax0);
        gather(ix1, cfB0v, cfB1v, ax1);

        // chain0 h1; chain1 h1 compute overlaps chain0's LDS/MFMA phases
        unsigned int hp0[8], hp1[8];
        h1comp(pox0, poy0, poz0, pi00, pi01, pi02, hp0);
        f16x8 af0[4];
        stage_af(hp0, af0);
        h1comp(pox1, poy1, poz1, pi10, pi11, pi12, hp1);   // VALU under LDS latency

        h2tile(af0);
        pacc(ax0, invA0, invA1, pA0l, pA0h, pA1l, pA1h);

        f16x8 af1[4];
        stage_af(hp1, af1);    // ds-writes ordered after chain0's bb reads
        h2tile(af1);
        pacc(ax1, invB0, invB1, pB0l, pB0h, pB1l, pB1h);
    } else {
        // ===== GENERIC PATH (R20) =====
        run_pair(0, ix0, pox0, poy0, poz0, pi00, pi01, pi02, pA0l, pA0h, pA1l, pA1h);
        run_pair(1, ix1, pox1, poy1, poz1, pi10, pi11, pi12, pB0l, pB0h, pB1l, pB1h);
    }

    // ================= fused output GEMM (32-point M-tile) =================
    // A-tile: rows 0..31 = block-local points, 1024 f16 in k' order, 2048B/row,
    // 16B chunks XOR-swizzled by ((row&7)<<4). Overlays the dead staging
    // region; split-k partials live at 65536..73727.
    __syncthreads();   // all waves done with H2L staging
    {
        auto storeP = [&](int row, u32x4 lo, u32x4 hi) {
            unsigned int base = (unsigned int)(row * 2048 + q * 512 + r * 32);
            unsigned int swz = (unsigned int)((row & 7) << 4);
            *(u32x4*)(ldsraw + (base ^ swz)) = lo;
            *(u32x4*)(ldsraw + ((base + 16u) ^ swz)) = hi;
        };
        int row0 = wv * 4;
        storeP(row0 + 0, pA0l, pA0h);
        storeP(row0 + 1, pA1l, pA1h);
        storeP(row0 + 2, pB0l, pB0h);
        storeP(row0 + 3, pB1l, pB1h);
    }
    __syncthreads();
    {
        // wave wv: ntile nt = wv&3 (cols nt*16..+16), k-half kh = wv>>2.
        // 2 row-tiles per wave; each B-frag loaded once, used twice.
        int nt = wv & 3;
        int kh = wv >> 2;
        const short8* Bp = (const short8*)W3frag + (size_t)(kh * 64 + nt) * 64 + lane;
        f32x4 Cg0 = (f32x4){0.f, 0.f, 0.f, 0.f};
        f32x4 Cg1 = (f32x4){0.f, 0.f, 0.f, 0.f};
        unsigned int aswz = (unsigned int)((r & 7) << 4);
        unsigned int ab0 = (unsigned int)(r * 2048 + kh * 1024 + q * 16);
        unsigned int ab1 = ab0 + 16u * 2048u;
        #pragma unroll
        for (int kk = 0; kk < 16; ++kk) {
            f16x8 bf = __builtin_bit_cast(f16x8, Bp[kk * 256]);   // frag ((kh*16+kk)*4 + nt)
            f16x8 a0 = __builtin_bit_cast(f16x8,
                *(const u32x4*)(ldsraw + ((ab0 + (unsigned int)(kk * 64)) ^ aswz)));
            f16x8 a1 = __builtin_bit_cast(f16x8,
                *(const u32x4*)(ldsraw + ((ab1 + (unsigned int)(kk * 64)) ^ aswz)));
            Cg0 = __builtin_amdgcn_mfma_f32_16x16x32_f16(a0, bf, Cg0, 0, 0, 0);
            Cg1 = __builtin_amdgcn_mfma_f32_16x16x32_f16(a1, bf, Cg1, 0, 0, 0);
        }
        // split-k reduce: kh=1 waves publish partials, kh=0 waves combine.
        if (kh == 1) {
            *(f32x4*)(ldsraw + 65536 + (wv - 4) * 2048 + lane * 16) = Cg0;
            *(f32x4*)(ldsraw + 65536 + (wv - 4) * 2048 + 1024 + lane * 16) = Cg1;
        }
        __syncthreads();
        if (kh == 0) {
            f32x4 Cp0 = *(const f32x4*)(ldsraw + 65536 + wv * 2048 + lane * 16);
            f32x4 Cp1 = *(const f32x4*)(ldsraw + 65536 + wv * 2048 + 1024 + lane * 16);
            int colbase = nt * 16 + r;
            float bias = b3[colbase];
            #pragma unroll
            for (int i = 0; i < 4; ++i) {
                int prow0 = perm[blockIdx.x * 32 + q * 4 + i];
                out[(size_t)prow0 * 64 + colbase] = Cg0[i] + Cp0[i] + bias;
            }
            #pragma unroll
            for (int i = 0; i < 4; ++i) {
                int prow1 = perm[blockIdx.x * 32 + 16 + q * 4 + i];
                out[(size_t)prow1 * 64 + colbase] = Cg1[i] + Cp1[i] + bias;
            }
        }
    }
}

extern "C" void kernel_launch(void* const* d_in, const int* in_sizes, int n_in,
                              void* d_out, int out_size, void* d_ws, size_t ws_size,
                              hipStream_t stream)
{
    const float* x_in    = (const float*)d_in[0];
    const float* pos_in  = (const float*)d_in[1];
    const float* pos_out = (const float*)d_in[2];
    const int* in_index  = (const int*)d_in[3];
    const int* out_index = (const int*)d_in[4];
    const float* W1 = (const float*)d_in[5];
    const float* W2 = (const float*)d_in[6];
    const float* W3 = (const float*)d_in[7];
    const float* b3 = (const float*)d_in[8];

    int N = in_sizes[0] / 16;    // 32768
    int E = in_sizes[3];         // 786432
    float* out = (float*)d_out;

    // workspace: seg (N+1) | W3frag (128KB) | W2f16 (4KB) | perm (N) | cnts (2)
    char* ws = (char*)d_ws;
    int* seg = (int*)ws;
    size_t off = (((size_t)(N + 1) * 4 + 255) & ~(size_t)255);
    __fp16* W3frag = (__fp16*)(ws + off);
    off += (size_t)65536 * 2;
    unsigned int* W2f16 = (unsigned int*)(ws + off);
    off += (size_t)1024 * 4;
    int* perm = (int*)(ws + off);
    off += (size_t)N * 4;
    int* cnts = (int*)(ws + off);

    setup_kernel<<<(E + 255) / 256, 256, 0, stream>>>(out_index, seg, E, N,
                                                      W3, W2, W3frag, W2f16, cnts);
    sort_kernel<<<(N + 255) / 256, 256, 0, stream>>>(seg, perm, cnts, N);
    agg_kernel<<<N / 32, 512, 0, stream>>>(x_in, pos_in, pos_out, in_index, seg,
                                           perm, W1, W2f16, W3frag, b3, out, E);
}